// Round 6
// baseline (124.951 us; speedup 1.0000x reference)
//
#include <hip/hip_runtime.h>

// Problem constants
static constexpr int NQ    = 12;
static constexpr int DEPTH = 4;
static constexpr int LAT   = 512;
static constexpr int FAST  = DEPTH * NQ;   // 48
static constexpr float DECAY = 0.9f;

using v2f = __attribute__((ext_vector_type(2))) float;

// One wave = one batch element. 4096 amplitudes in 64 VGPRs/lane (L layout):
// i = (lane<<6) | r ; wire w <-> bit (11-w):
//   wires 0..5 -> lane bits 5..0 (M = 32..1), wires 6..11 -> reg bits 5..0 (S = 32..1)

__device__ __forceinline__ float i2f(int x) { return __int_as_float(x); }

// VALU-pipe lane-XOR partner fetch (verified rounds 3-4).
template<int M>
__device__ __forceinline__ float xpartner(float x, int lane) {
    int xi = __float_as_int(x);
    if constexpr (M == 1) {        // quad_perm [1,0,3,2]
        return i2f(__builtin_amdgcn_update_dpp(xi, xi, 0xB1, 0xF, 0xF, true));
    } else if constexpr (M == 2) { // quad_perm [2,3,0,1]
        return i2f(__builtin_amdgcn_update_dpp(xi, xi, 0x4E, 0xF, 0xF, true));
    } else if constexpr (M == 4) { // row_half_mirror (xor7) then quad reverse (xor3)
        int t = __builtin_amdgcn_update_dpp(xi, xi, 0x141, 0xF, 0xF, true);
        return i2f(__builtin_amdgcn_update_dpp(t, t, 0x1B, 0xF, 0xF, true));
    } else if constexpr (M == 8) { // row_ror:8 == xor8 within 16-lane rows
        return i2f(__builtin_amdgcn_update_dpp(xi, xi, 0x128, 0xF, 0xF, true));
    } else if constexpr (M == 16) {
#if __has_builtin(__builtin_amdgcn_permlane16_swap)
        auto r = __builtin_amdgcn_permlane16_swap((unsigned)xi, (unsigned)xi, false, false);
        return i2f((int)(r[0] ^ r[1]) ^ xi);   // {own,partner} -> partner
#else
        return __shfl_xor(x, 16, 64);
#endif
    } else {
#if __has_builtin(__builtin_amdgcn_permlane32_swap)
        auto r = __builtin_amdgcn_permlane32_swap((unsigned)xi, (unsigned)xi, false, false);
        return i2f((int)(r[0] ^ r[1]) ^ xi);
#else
        return __shfl_xor(x, 32, 64);
#endif
    }
}

// RY on lane wire W in [0,5], packed arithmetic (2 regs per iteration).
template<int W>
__device__ __forceinline__ void ry_lane(float (&v)[64], int lane, float c, float s) {
    constexpr int M = 1 << (5 - W);
    float t = (lane & M) ? s : -s;
    v2f cc = {c, c}, tt = {t, t};
    #pragma unroll
    for (int k = 0; k < 32; k++) {
        float p0 = xpartner<M>(v[2 * k],     lane);
        float p1 = xpartner<M>(v[2 * k + 1], lane);
        v2f vv = {v[2 * k], v[2 * k + 1]};
        v2f pp = {p0, p1};
        vv = cc * vv + tt * pp;            // v_pk_fma_f32
        v[2 * k]     = vv.x;
        v[2 * k + 1] = vv.y;
    }
}

// RY on register wire W in [6,11], packed butterflies.
template<int W>
__device__ __forceinline__ void ry_reg(float (&v)[64], float c, float s) {
    constexpr int S = 1 << (11 - W);
    if constexpr (S >= 2) {
        v2f cc = {c, c}, ss = {s, s};
        #pragma unroll
        for (int r0 = 0; r0 < 64; r0 += 2) {
            if ((r0 & S) == 0) {
                v2f a = {v[r0],     v[r0 + 1]};
                v2f b = {v[r0 + S], v[r0 + S + 1]};
                v2f na = cc * a - ss * b;
                v2f nb = ss * a + cc * b;
                v[r0]         = na.x;  v[r0 + 1]     = na.y;
                v[r0 + S]     = nb.x;  v[r0 + S + 1] = nb.y;
            }
        }
    } else {  // S == 1: pair is adjacent regs; coeff-vector + op_sel broadcasts
        v2f cs = {c, s}, nsc = {-s, c};
        #pragma unroll
        for (int r0 = 0; r0 < 64; r0 += 2) {
            float a = v[r0], b = v[r0 + 1];
            v2f aa = {a, a}, bb = {b, b};
            v2f res = cs * aa + nsc * bb;   // (c*a - s*b, s*a + c*b)
            v[r0]     = res.x;
            v[r0 + 1] = res.y;
        }
    }
}

// CNOT(W,W+1) for W in [6,10]: compile-time register renames, ~free (verified r3).
template<int W>
__device__ __forceinline__ void apply_cnot_reg(float (&v)[64]) {
    constexpr int CBS = 1 << (11 - W);
    constexpr int TBS = 1 << (10 - W);
    #pragma unroll
    for (int r = 0; r < 64; r++) {
        if ((r & CBS) != 0 && (r & TBS) == 0) {
            float tmp = v[r];
            v[r]       = v[r | TBS];
            v[r | TBS] = tmp;
        }
    }
}

template<int W>
__device__ __forceinline__ void cnot_reg_chain(float (&v)[64]) {
    if constexpr (W < 11) {
        apply_cnot_reg<W>(v);
        cnot_reg_chain<W + 1>(v);
    }
}

template<int W>
__device__ __forceinline__ void layer_rys(float (&v)[64], int lane,
                                          const float* lc, const float* ls) {
    if constexpr (W < 12) {
        if constexpr (W < 6) ry_lane<W>(v, lane, lc[W], ls[W]);
        else                 ry_reg<W>(v, lc[W], ls[W]);
        layer_rys<W + 1>(v, lane, lc, ls);
    }
}

__global__ __launch_bounds__(64, 2)
void fwp_kernel(const float* __restrict__ x_t,
                const float* __restrict__ fast_prev,
                const float* __restrict__ W_enc,
                const float* __restrict__ b_enc,
                const float* __restrict__ W_upd,
                const float* __restrict__ b_upd,
                const float* __restrict__ W_ro,
                const float* __restrict__ b_ro,
                float* __restrict__ out_y,
                float* __restrict__ out_fast) {
    const int lane = threadIdx.x;   // block = one wave
    const int b    = blockIdx.x;

    __shared__ __align__(16) float s_lat[LAT];     // 2 KB latent
    __shared__ float s_c[FAST], s_s[FAST];         // per-gate cos/sin

    // ---- x broadcast ----
    float xr = (lane < NQ) ? x_t[b * NQ + lane] : 0.0f;
    float xa[NQ];
    #pragma unroll
    for (int k = 0; k < NQ; k++) xa[k] = __shfl(xr, k, 64);

    // ---- Phase A: latent = tanh(W_enc@x + b_enc), 8 per lane ----
    #pragma unroll
    for (int t = 0; t < LAT / 64; t++) {
        int j = lane + 64 * t;
        const float4* wr = (const float4*)(W_enc + j * NQ);
        float4 a0 = wr[0], a1 = wr[1], a2 = wr[2];
        float sum = b_enc[j]
            + a0.x * xa[0] + a0.y * xa[1] + a0.z * xa[2]  + a0.w * xa[3]
            + a1.x * xa[4] + a1.y * xa[5] + a1.z * xa[6]  + a1.w * xa[7]
            + a2.x * xa[8] + a2.y * xa[9] + a2.z * xa[10] + a2.w * xa[11];
        s_lat[j] = tanhf(sum);
    }
    __syncthreads();

    // ---- Phase B: 48 angles; lane o<48 owns one W_upd row; cos/sin to LDS ----
    if (lane < FAST) {
        const float4* wr = (const float4*)(W_upd + lane * LAT);
        const float4* lr = (const float4*)(s_lat);
        float sum = b_upd[lane];
        #pragma unroll 16
        for (int j = 0; j < LAT / 4; j++) {
            float4 w4 = wr[j];
            float4 l4 = lr[j];   // uniform address -> LDS broadcast
            sum += w4.x * l4.x + w4.y * l4.y + w4.z * l4.z + w4.w * l4.w;
        }
        float ang = DECAY * fast_prev[b * FAST + lane] + sum;
        out_fast[b * FAST + lane] = ang;
        float hh = 0.5f * ang;
        s_c[lane] = __cosf(hh);
        s_s[lane] = __sinf(hh);
    }
    __syncthreads();

    // ---- closed-form product-state init (L orientation) ----
    float g0[NQ], g1[NQ];
    #pragma unroll
    for (int w = 0; w < NQ; w++) {
        float hh = 0.5f * xa[w];
        float c = __cosf(hh), s = __sinf(hh);
        g0[w] = (c - s) * 0.70710678118654752f;
        g1[w] = (c + s) * 0.70710678118654752f;
    }
    float L = 1.0f;
    #pragma unroll
    for (int w = 0; w < 6; w++)
        L *= ((lane >> (5 - w)) & 1) ? g1[w] : g0[w];

    float v[64];
    v[0] = L;
    #pragma unroll
    for (int w = 6; w < NQ; w++) {
        const int S = 1 << (11 - w);
        #pragma unroll
        for (int r = 0; r < 64; r += 2 * S) {
            v[r + S] = v[r] * g1[w];
            v[r]     = v[r] * g0[w];
        }
    }

    // ---- composed lane permutation for CNOT(0,1)..(4,5) (verified r3) ----
    int csrc = lane;
    #pragma unroll
    for (int w = 4; w >= 0; w--)
        csrc ^= ((csrc >> (5 - w)) & 1) << (4 - w);
    const int csrc4 = csrc << 2;

    // ---- 4 layers ----
    #pragma unroll 1
    for (int layer = 0; layer < DEPTH; layer++) {
        // hoist this layer's 12 cos/sin pairs (uniform LDS broadcast reads)
        float lc[NQ], ls[NQ];
        #pragma unroll
        for (int w = 0; w < NQ; w++) {
            lc[w] = s_c[layer * NQ + w];
            ls[w] = s_s[layer * NQ + w];
        }
        // CNOT(0,1)..(4,5): one composed lane gather per register
        #pragma unroll
        for (int r = 0; r < 64; r++)
            v[r] = i2f(__builtin_amdgcn_ds_bpermute(csrc4, __float_as_int(v[r])));
        // CNOT(5,6): control = lane bit0, target = reg bit5
        bool c5 = (lane & 1) != 0;
        #pragma unroll
        for (int r0 = 0; r0 < 32; r0++) {
            float a = v[r0], bb = v[r0 + 32];
            v[r0]      = c5 ? bb : a;
            v[r0 + 32] = c5 ? a : bb;
        }
        // CNOT(6,7)..(10,11): free register renames
        cnot_reg_chain<6>(v);
        // 12 RYs: lane wires via DPP/permlane + pk-fma, reg wires via pk butterflies
        layer_rys<0>(v, lane, lc, ls);
    }

    // ---- Z expectations folded into readout (verified r5) ----
    float tot = 0.0f, pw[6] = {0, 0, 0, 0, 0, 0};
    #pragma unroll
    for (int r = 0; r < 64; r++) {
        float p = v[r] * v[r];
        tot += p;
        pw[0] += (r & 32) ? -p : p;   // wire 6
        pw[1] += (r & 16) ? -p : p;   // wire 7
        pw[2] += (r & 8)  ? -p : p;   // wire 8
        pw[3] += (r & 4)  ? -p : p;   // wire 9
        pw[4] += (r & 2)  ? -p : p;   // wire 10
        pw[5] += (r & 1)  ? -p : p;   // wire 11
    }
    float sl = 0.0f;
    #pragma unroll
    for (int w = 0; w < 6; w++) {
        float c = W_ro[w];
        sl += ((lane >> (5 - w)) & 1) ? -c : c;
    }
    float y = sl * tot;
    #pragma unroll
    for (int k = 0; k < 6; k++) y += W_ro[6 + k] * pw[k];
    #pragma unroll
    for (int m = 32; m >= 1; m >>= 1) y += __shfl_xor(y, m, 64);
    if (lane == 0) out_y[b] = y + b_ro[0];
}

extern "C" void kernel_launch(void* const* d_in, const int* in_sizes, int n_in,
                              void* d_out, int out_size, void* d_ws, size_t ws_size,
                              hipStream_t stream) {
    const float* x_t       = (const float*)d_in[0];
    const float* fast_prev = (const float*)d_in[1];
    const float* W_enc     = (const float*)d_in[2];
    const float* b_enc     = (const float*)d_in[3];
    const float* W_upd     = (const float*)d_in[4];
    const float* b_upd     = (const float*)d_in[5];
    const float* W_ro      = (const float*)d_in[6];
    const float* b_ro      = (const float*)d_in[7];
    float* out = (float*)d_out;

    fwp_kernel<<<2048, 64, 0, stream>>>(x_t, fast_prev, W_enc, b_enc,
                                        W_upd, b_upd, W_ro, b_ro,
                                        out /*y*/, out + 2048 /*fast_next*/);
}

// Round 7
// 111.255 us; speedup vs baseline: 1.1231x; 1.1231x over previous
//
#include <hip/hip_runtime.h>

// Problem constants
static constexpr int NQ    = 12;
static constexpr int DEPTH = 4;
static constexpr int LAT   = 512;
static constexpr int FAST  = DEPTH * NQ;   // 48
static constexpr float DECAY = 0.9f;
static constexpr int PITCH = 66;           // even (b64-aligned), 2-way bank alias = free

using v2f = __attribute__((ext_vector_type(2))) float;

// One wave = one batch element; block = exactly one wave (wave-synchronous).
// L orientation: i = (lane<<6) | r   (wires 0..5 lane bits, 6..11 reg bits)
// T orientation: i = (r<<6) | lane   (wires 0..5 reg bits, 6..11 lane bits)
// Layer = RY(12 wires) ∘ CNOT-chain(0..10); CNOT chain sigma is GF(2)-linear:
// sigma^-1: bit_p = j_p ^ j_{p+1}. Pass 1 folds sigma + L->T into LDS read
// addressing; R_lo (wires 0..5) become register butterflies in T. Pass 2
// transposes back; R_hi (wires 6..11) are register butterflies in L.
// No barriers: intra-wave LDS ops execute in order; we only need
// compiler-ordering (wave_barrier, free) at WAR edges and an lgkm drain
// (__threadfence_block) at RAW edges.

#define RAW_FENCE() __threadfence_block()
#define WAR_FENCE() __builtin_amdgcn_wave_barrier()

// Packed RY butterfly, stride S>=2: pairs (r0,r0+S), two pairs per pk-op set.
template<int S>
__device__ __forceinline__ void bfly2(float (&v)[64], float c, float s) {
    v2f c2 = {c, c}, s2 = {s, s};
    #pragma unroll
    for (int r0 = 0; r0 < 64; r0 += 2) {
        if ((r0 & S) == 0) {
            v2f a = {v[r0],     v[r0 + 1]};
            v2f b = {v[r0 + S], v[r0 + S + 1]};
            v2f na = c2 * a - s2 * b;      // pk_mul + pk_fma(neg)
            v2f nb = s2 * a + c2 * b;      // pk_mul + pk_fma
            v[r0]         = na.x;  v[r0 + 1]     = na.y;
            v[r0 + S]     = nb.x;  v[r0 + S + 1] = nb.y;
        }
    }
}

// Stride-1 butterfly: pair inside adjacent regs; coefficient-vector form.
__device__ __forceinline__ void bfly1(float (&v)[64], float c, float s) {
    v2f cs = {c, s}, nsc = {-s, c};
    #pragma unroll
    for (int r0 = 0; r0 < 64; r0 += 2) {
        float a = v[r0], b = v[r0 + 1];
        v2f aa = {a, a}, bb = {b, b};
        v2f res = cs * aa + nsc * bb;      // (c*a - s*b, s*a + c*b)
        v[r0]     = res.x;
        v[r0 + 1] = res.y;
    }
}

// 6 RYs on register bits 5..0 (strides 32,16,8,4,2,1)
__device__ __forceinline__ void ry6(float (&v)[64], const float* lc, const float* ls) {
    bfly2<32>(v, lc[0], ls[0]);
    bfly2<16>(v, lc[1], ls[1]);
    bfly2<8>(v, lc[2], ls[2]);
    bfly2<4>(v, lc[3], ls[3]);
    bfly2<2>(v, lc[4], ls[4]);
    bfly1(v, lc[5], ls[5]);
}

__global__ __launch_bounds__(64, 2)
void fwp_kernel(const float* __restrict__ x_t,
                const float* __restrict__ fast_prev,
                const float* __restrict__ W_enc,
                const float* __restrict__ b_enc,
                const float* __restrict__ W_upd,
                const float* __restrict__ b_upd,
                const float* __restrict__ W_ro,
                const float* __restrict__ b_ro,
                float* __restrict__ out_y,
                float* __restrict__ out_fast) {
    const int lane = threadIdx.x;   // block = one wave
    const int b    = blockIdx.x;

    __shared__ __align__(16) float s_xch[64 * PITCH];  // 16.9 KB transpose buffer
    __shared__ float s_c[FAST], s_s[FAST];             // per-gate cos/sin

    float* s_lat = s_xch;   // latent reuses the buffer (dead before layer 0)

    // ---- x broadcast ----
    float xr = (lane < NQ) ? x_t[b * NQ + lane] : 0.0f;
    float xa[NQ];
    #pragma unroll
    for (int k = 0; k < NQ; k++) xa[k] = __shfl(xr, k, 64);

    // ---- Phase A: latent = tanh(W_enc@x + b_enc), 8 per lane ----
    #pragma unroll
    for (int t = 0; t < LAT / 64; t++) {
        int j = lane + 64 * t;
        const float4* wr = (const float4*)(W_enc + j * NQ);
        float4 a0 = wr[0], a1 = wr[1], a2 = wr[2];
        float sum = b_enc[j]
            + a0.x * xa[0] + a0.y * xa[1] + a0.z * xa[2]  + a0.w * xa[3]
            + a1.x * xa[4] + a1.y * xa[5] + a1.z * xa[6]  + a1.w * xa[7]
            + a2.x * xa[8] + a2.y * xa[9] + a2.z * xa[10] + a2.w * xa[11];
        s_lat[j] = tanhf(sum);
    }
    RAW_FENCE();   // s_lat writes -> cross-lane reads (same wave, in-order LDS)

    // ---- Phase B: 48 angles; lane o<48 owns one W_upd row; cos/sin to LDS ----
    if (lane < FAST) {
        const float4* wr = (const float4*)(W_upd + lane * LAT);
        const float4* lr = (const float4*)(s_lat);
        float sum = b_upd[lane];
        #pragma unroll 16
        for (int j = 0; j < LAT / 4; j++) {
            float4 w4 = wr[j];
            float4 l4 = lr[j];   // uniform address -> LDS broadcast
            sum += w4.x * l4.x + w4.y * l4.y + w4.z * l4.z + w4.w * l4.w;
        }
        float ang = DECAY * fast_prev[b * FAST + lane] + sum;
        out_fast[b * FAST + lane] = ang;
        float hh = 0.5f * ang;
        s_c[lane] = __cosf(hh);
        s_s[lane] = __sinf(hh);
    }
    RAW_FENCE();   // s_c/s_s writes -> all-lane reads

    // ---- closed-form product-state init (L orientation) ----
    float g0[NQ], g1[NQ];
    #pragma unroll
    for (int w = 0; w < NQ; w++) {
        float hh = 0.5f * xa[w];
        float c = __cosf(hh), s = __sinf(hh);
        g0[w] = (c - s) * 0.70710678118654752f;
        g1[w] = (c + s) * 0.70710678118654752f;
    }
    float L = 1.0f;
    #pragma unroll
    for (int w = 0; w < 6; w++)
        L *= ((lane >> (5 - w)) & 1) ? g1[w] : g0[w];

    float v[64];
    v[0] = L;
    #pragma unroll
    for (int w = 6; w < NQ; w++) {
        const int S = 1 << (11 - w);
        #pragma unroll
        for (int r = 0; r < 64; r += 2 * S) {
            v[r + S] = v[r] * g1[w];
            v[r]     = v[r] * g0[w];
        }
    }

    // Pass-1 read bases (verified r5): src reg = gray(lane) low5 | lane bit5, ^32 if r odd
    const int A0 = ((lane ^ (lane >> 1)) & 31) | (lane & 32);
    const int A1 = A0 ^ 32;

    // ---- 4 layers, fully unrolled, no barriers ----
    #pragma unroll
    for (int layer = 0; layer < DEPTH; layer++) {
        float lc[NQ], ls[NQ];
        #pragma unroll
        for (int w = 0; w < NQ; w++) {
            lc[w] = s_c[layer * NQ + w];
            ls[w] = s_s[layer * NQ + w];
        }

        // Pass 1: write L rows (b64), read back with sigma + transpose folded in
        WAR_FENCE();   // don't sink writes above previous pass's reads
        #pragma unroll
        for (int k = 0; k < 32; k++)
            *(v2f*)&s_xch[lane * PITCH + 2 * k] = (v2f){v[2 * k], v[2 * k + 1]};
        RAW_FENCE();
        #pragma unroll
        for (int r = 0; r < 64; r++) {
            const int g = r ^ (r >> 1);     // compile-time immediate offset
            v[r] = s_xch[g * PITCH + ((r & 1) ? A1 : A0)];
        }
        // RY wires 0..5 (register bits in T)
        ry6(v, lc, ls);

        // Pass 2: plain transpose T->L
        WAR_FENCE();
        #pragma unroll
        for (int k = 0; k < 32; k++)
            *(v2f*)&s_xch[lane * PITCH + 2 * k] = (v2f){v[2 * k], v[2 * k + 1]};
        RAW_FENCE();
        #pragma unroll
        for (int r = 0; r < 64; r++) v[r] = s_xch[r * PITCH + lane];
        // RY wires 6..11 (register bits in L)
        ry6(v, lc + 6, ls + 6);
    }

    // ---- Z expectations folded into readout (L orientation, verified r5) ----
    float tot = 0.0f, pw[6] = {0, 0, 0, 0, 0, 0};
    #pragma unroll
    for (int r = 0; r < 64; r++) {
        float p = v[r] * v[r];
        tot += p;
        pw[0] += (r & 32) ? -p : p;   // wire 6
        pw[1] += (r & 16) ? -p : p;   // wire 7
        pw[2] += (r & 8)  ? -p : p;   // wire 8
        pw[3] += (r & 4)  ? -p : p;   // wire 9
        pw[4] += (r & 2)  ? -p : p;   // wire 10
        pw[5] += (r & 1)  ? -p : p;   // wire 11
    }
    float sl = 0.0f;
    #pragma unroll
    for (int w = 0; w < 6; w++) {
        float c = W_ro[w];
        sl += ((lane >> (5 - w)) & 1) ? -c : c;
    }
    float y = sl * tot;
    #pragma unroll
    for (int k = 0; k < 6; k++) y += W_ro[6 + k] * pw[k];
    #pragma unroll
    for (int m = 32; m >= 1; m >>= 1) y += __shfl_xor(y, m, 64);
    if (lane == 0) out_y[b] = y + b_ro[0];
}

extern "C" void kernel_launch(void* const* d_in, const int* in_sizes, int n_in,
                              void* d_out, int out_size, void* d_ws, size_t ws_size,
                              hipStream_t stream) {
    const float* x_t       = (const float*)d_in[0];
    const float* fast_prev = (const float*)d_in[1];
    const float* W_enc     = (const float*)d_in[2];
    const float* b_enc     = (const float*)d_in[3];
    const float* W_upd     = (const float*)d_in[4];
    const float* b_upd     = (const float*)d_in[5];
    const float* W_ro      = (const float*)d_in[6];
    const float* b_ro      = (const float*)d_in[7];
    float* out = (float*)d_out;

    fwp_kernel<<<2048, 64, 0, stream>>>(x_t, fast_prev, W_enc, b_enc,
                                        W_upd, b_upd, W_ro, b_ro,
                                        out /*y*/, out + 2048 /*fast_next*/);
}